// Round 3
// baseline (2178.502 us; speedup 1.0000x reference)
//
#include <hip/hip_runtime.h>
#include <math.h>

#define HID  128
#define EDIM 4

typedef unsigned short u16;
typedef u16    us8   __attribute__((ext_vector_type(8)));
typedef __bf16 bf16x8 __attribute__((ext_vector_type(8)));
typedef float  f32x4 __attribute__((ext_vector_type(4)));

__device__ __forceinline__ float silu_f(float v) {
    return v / (1.0f + __expf(-v));
}
__device__ __forceinline__ u16 f2bf(float f) {   // RNE fp32->bf16
    unsigned u = __float_as_uint(f);
    unsigned r = u + 0x7fffu + ((u >> 16) & 1u);
    return (u16)(r >> 16);
}
__device__ __forceinline__ float bf2f(u16 s) {
    return __uint_as_float(((unsigned)s) << 16);
}
__device__ __forceinline__ bf16x8 as_bf(us8 v) {
    return __builtin_bit_cast(bf16x8, v);
}

// ---------------- prep kernels (run every call; ws is re-poisoned) ----------

// Swizzle weights [L][K][128] fp32 -> MFMA B-fragments bf16:
// out[((l*KT*8 + kt*8+nt)*64 + lane)*8 + j] = W[l][kt*32+(lane>>4)*8+j][nt*16+(lane&15)]
__global__ __launch_bounds__(256) void prep_wfrag(const float* __restrict__ w,
        u16* __restrict__ out, int KT, int K, int total) {
    int idx = blockIdx.x * 256 + threadIdx.x;
    if (idx >= total) return;
    int lane = idx & 63;
    int f    = (idx >> 6) % (KT * 8);
    int l    = idx / (64 * KT * 8);
    int kt = f >> 3, nt = f & 7;
    int n  = nt * 16 + (lane & 15);
    int k0 = kt * 32 + ((lane >> 4) * 8);
    us8 v;
    #pragma unroll
    for (int j = 0; j < 8; ++j) {
        int k = k0 + j;
        v[j] = (k < K) ? f2bf(w[((size_t)l * K + k) * HID + n]) : (u16)0;
    }
    *(us8*)&out[((size_t)(l * KT * 8 + f) * 64 + lane) * 8] = v;
}

__global__ __launch_bounds__(256) void prep_ea(const float* __restrict__ ea,
        u16* __restrict__ eab, int total) {
    int i = blockIdx.x * 256 + threadIdx.x;
    if (i < total) eab[i] = f2bf(ea[i]);
}

__global__ __launch_bounds__(HID) void embed_kernel(const int* __restrict__ z,
        const float* __restrict__ emb, u16* __restrict__ xb, int n) {
    int i = blockIdx.x;
    if (i >= n) return;
    int t = threadIdx.x;
    xb[(size_t)i * HID + t] = f2bf(emb[(size_t)z[i] * HID + t]);
}

// ---------------- edge MLP: 64 edges/block, A gathered direct to regs -------
__global__ __launch_bounds__(256) void edge_mfma(
        const u16* __restrict__ xb, const int* __restrict__ src,
        const int* __restrict__ dst, const u16* __restrict__ eab,
        const u16* __restrict__ w1f, const float* __restrict__ b1,
        const u16* __restrict__ w2f, const float* __restrict__ b2,
        float* __restrict__ agg, int nE) {
    __shared__ u16 H[64 * 136];   // stride 136 u16 = 17*8, b128-aligned rows
    __shared__ int dsh[64];
    const int t    = threadIdx.x;
    const int e0   = blockIdx.x * 64;
    const int wv   = t >> 6, lane = t & 63;
    const int lrow = lane & 15;
    const int kq   = lane >> 4;      // 0..3
    const int kq8  = kq * 8;
    const int rq   = kq * 4;

    if (t < 64) {
        int e = e0 + t; if (e >= nE) e = nE - 1;
        dsh[t] = dst[e];
    }

    // per-lane A row ids (4 m-tiles of 16 rows)
    int sN[4], dN[4], eIdx[4];
    #pragma unroll
    for (int mt = 0; mt < 4; ++mt) {
        int e = e0 + mt * 16 + lrow; if (e >= nE) e = nE - 1;
        eIdx[mt] = e; sN[mt] = src[e]; dN[mt] = dst[e];
    }

    // ---- GEMM1: [64 x 288] @ [288 x 128] (wave owns 32 cols) ----
    f32x4 acc[4][2];
    {
        float bias0 = b1[wv * 32 + lrow], bias1 = b1[wv * 32 + 16 + lrow];
        #pragma unroll
        for (int mt = 0; mt < 4; ++mt)
            #pragma unroll
            for (int r = 0; r < 4; ++r) {
                acc[mt][0][r] = bias0; acc[mt][1][r] = bias1;
            }
    }
    #pragma unroll
    for (int kt = 0; kt < 8; ++kt) {     // x_src (kt<4) then x_dst
        bf16x8 w0 = *(const bf16x8*)&w1f[((size_t)(kt * 8 + wv * 2 + 0) * 64 + lane) * 8];
        bf16x8 w1 = *(const bf16x8*)&w1f[((size_t)(kt * 8 + wv * 2 + 1) * 64 + lane) * 8];
        #pragma unroll
        for (int mt = 0; mt < 4; ++mt) {
            int node = (kt < 4) ? sN[mt] : dN[mt];
            bf16x8 a = as_bf(*(const us8*)&xb[(size_t)node * HID + (kt & 3) * 32 + kq8]);
            acc[mt][0] = __builtin_amdgcn_mfma_f32_16x16x32_bf16(a, w0, acc[mt][0], 0, 0, 0);
            acc[mt][1] = __builtin_amdgcn_mfma_f32_16x16x32_bf16(a, w1, acc[mt][1], 0, 0, 0);
        }
    }
    {   // kt = 8: ea occupies k 256..259; W rows >=260 are zero from prep,
        // so only kq==0 lanes' first 4 elements matter.
        bf16x8 w0 = *(const bf16x8*)&w1f[((size_t)(8 * 8 + wv * 2 + 0) * 64 + lane) * 8];
        bf16x8 w1 = *(const bf16x8*)&w1f[((size_t)(8 * 8 + wv * 2 + 1) * 64 + lane) * 8];
        #pragma unroll
        for (int mt = 0; mt < 4; ++mt) {
            us8 av = {0, 0, 0, 0, 0, 0, 0, 0};
            if (kq == 0) {
                const u16* p = &eab[(size_t)eIdx[mt] * EDIM];
                av[0] = p[0]; av[1] = p[1]; av[2] = p[2]; av[3] = p[3];
            }
            bf16x8 a = as_bf(av);
            acc[mt][0] = __builtin_amdgcn_mfma_f32_16x16x32_bf16(a, w0, acc[mt][0], 0, 0, 0);
            acc[mt][1] = __builtin_amdgcn_mfma_f32_16x16x32_bf16(a, w1, acc[mt][1], 0, 0, 0);
        }
    }
    // silu -> H (LDS layout transform C-layout -> A-layout)
    #pragma unroll
    for (int mt = 0; mt < 4; ++mt)
        #pragma unroll
        for (int nt2 = 0; nt2 < 2; ++nt2)
            #pragma unroll
            for (int r = 0; r < 4; ++r)
                H[(mt * 16 + rq + r) * 136 + wv * 32 + nt2 * 16 + lrow] =
                    f2bf(silu_f(acc[mt][nt2][r]));
    __syncthreads();

    // ---- GEMM2: [64 x 128] @ [128 x 128] ----
    f32x4 acc2[4][2];
    {
        float bias0 = b2[wv * 32 + lrow], bias1 = b2[wv * 32 + 16 + lrow];
        #pragma unroll
        for (int mt = 0; mt < 4; ++mt)
            #pragma unroll
            for (int r = 0; r < 4; ++r) {
                acc2[mt][0][r] = bias0; acc2[mt][1][r] = bias1;
            }
    }
    #pragma unroll
    for (int kt = 0; kt < 4; ++kt) {
        bf16x8 w0 = *(const bf16x8*)&w2f[((size_t)(kt * 8 + wv * 2 + 0) * 64 + lane) * 8];
        bf16x8 w1 = *(const bf16x8*)&w2f[((size_t)(kt * 8 + wv * 2 + 1) * 64 + lane) * 8];
        #pragma unroll
        for (int mt = 0; mt < 4; ++mt) {
            bf16x8 a = *(const bf16x8*)&H[(mt * 16 + lrow) * 136 + kt * 32 + kq8];
            acc2[mt][0] = __builtin_amdgcn_mfma_f32_16x16x32_bf16(a, w0, acc2[mt][0], 0, 0, 0);
            acc2[mt][1] = __builtin_amdgcn_mfma_f32_16x16x32_bf16(a, w1, acc2[mt][1], 0, 0, 0);
        }
    }
    // silu -> atomic scatter
    #pragma unroll
    for (int mt = 0; mt < 4; ++mt)
        #pragma unroll
        for (int nt2 = 0; nt2 < 2; ++nt2)
            #pragma unroll
            for (int r = 0; r < 4; ++r) {
                int row = mt * 16 + rq + r;
                if (e0 + row < nE) {
                    int col = wv * 32 + nt2 * 16 + lrow;
                    unsafeAtomicAdd(&agg[(size_t)dsh[row] * HID + col],
                                    silu_f(acc2[mt][nt2][r]));
                }
            }
}

// ---------------- node MLP: 64 nodes/block, no LDS, in-place ----------------
__global__ __launch_bounds__(256) void node_mfma(
        u16* __restrict__ xb, const float* __restrict__ agg,
        const u16* __restrict__ nwf, const float* __restrict__ nb, int n) {
    const int t    = threadIdx.x;
    const int i0   = blockIdx.x * 64;
    const int wv   = t >> 6, lane = t & 63;
    const int lrow = lane & 15;
    const int kq   = lane >> 4;
    const int kq8  = kq * 8;
    const int rq   = kq * 4;

    int iN[4];
    #pragma unroll
    for (int mt = 0; mt < 4; ++mt) {
        int i = i0 + mt * 16 + lrow; if (i >= n) i = n - 1;
        iN[mt] = i;
    }

    f32x4 acc[4][2];
    {
        float bias0 = nb[wv * 32 + lrow], bias1 = nb[wv * 32 + 16 + lrow];
        #pragma unroll
        for (int mt = 0; mt < 4; ++mt)
            #pragma unroll
            for (int r = 0; r < 4; ++r) {
                acc[mt][0][r] = bias0; acc[mt][1][r] = bias1;
            }
    }
    #pragma unroll
    for (int kt = 0; kt < 4; ++kt) {     // x part (k 0..127)
        bf16x8 w0 = *(const bf16x8*)&nwf[((size_t)(kt * 8 + wv * 2 + 0) * 64 + lane) * 8];
        bf16x8 w1 = *(const bf16x8*)&nwf[((size_t)(kt * 8 + wv * 2 + 1) * 64 + lane) * 8];
        #pragma unroll
        for (int mt = 0; mt < 4; ++mt) {
            bf16x8 a = as_bf(*(const us8*)&xb[(size_t)iN[mt] * HID + kt * 32 + kq8]);
            acc[mt][0] = __builtin_amdgcn_mfma_f32_16x16x32_bf16(a, w0, acc[mt][0], 0, 0, 0);
            acc[mt][1] = __builtin_amdgcn_mfma_f32_16x16x32_bf16(a, w1, acc[mt][1], 0, 0, 0);
        }
    }
    #pragma unroll
    for (int kt = 4; kt < 8; ++kt) {     // agg part (k 128..255), fp32 -> bf16
        bf16x8 w0 = *(const bf16x8*)&nwf[((size_t)(kt * 8 + wv * 2 + 0) * 64 + lane) * 8];
        bf16x8 w1 = *(const bf16x8*)&nwf[((size_t)(kt * 8 + wv * 2 + 1) * 64 + lane) * 8];
        #pragma unroll
        for (int mt = 0; mt < 4; ++mt) {
            const float* p = &agg[(size_t)iN[mt] * HID + (kt - 4) * 32 + kq8];
            float4 f0 = *(const float4*)p;
            float4 f1 = *(const float4*)(p + 4);
            us8 av;
            av[0] = f2bf(f0.x); av[1] = f2bf(f0.y); av[2] = f2bf(f0.z); av[3] = f2bf(f0.w);
            av[4] = f2bf(f1.x); av[5] = f2bf(f1.y); av[6] = f2bf(f1.z); av[7] = f2bf(f1.w);
            bf16x8 a = as_bf(av);
            acc[mt][0] = __builtin_amdgcn_mfma_f32_16x16x32_bf16(a, w0, acc[mt][0], 0, 0, 0);
            acc[mt][1] = __builtin_amdgcn_mfma_f32_16x16x32_bf16(a, w1, acc[mt][1], 0, 0, 0);
        }
    }
    // all loads complete (consumed by MFMA); barrier prevents intra-block WAR
    __syncthreads();
    #pragma unroll
    for (int mt = 0; mt < 4; ++mt)
        #pragma unroll
        for (int nt2 = 0; nt2 < 2; ++nt2)
            #pragma unroll
            for (int r = 0; r < 4; ++r) {
                int row = mt * 16 + rq + r;
                int i = i0 + row;
                if (i < n) {
                    int col = wv * 32 + nt2 * 16 + lrow;
                    xb[(size_t)i * HID + col] = f2bf(silu_f(acc[mt][nt2][r]));
                }
            }
}

// ---------------- readout ---------------------------------------------------
__global__ __launch_bounds__(HID) void segsum_kernel(
        const u16* __restrict__ xb, const int* __restrict__ batch,
        float* __restrict__ sums, float* __restrict__ counts, int n) {
    int i = blockIdx.x;
    if (i >= n) return;
    int t = threadIdx.x;
    int b = batch[i];
    unsafeAtomicAdd(&sums[(size_t)b * HID + t], bf2f(xb[(size_t)i * HID + t]));
    if (t == 0) unsafeAtomicAdd(&counts[b], 1.0f);
}

__global__ __launch_bounds__(HID) void readout_kernel(
        const float* __restrict__ sums, const float* __restrict__ counts,
        const float* __restrict__ rw1, const float* __restrict__ rb1,
        const float* __restrict__ rw2, const float* __restrict__ rb2,
        float* __restrict__ pred) {
    __shared__ float gv[HID];
    __shared__ float hv[HID];
    const int g = blockIdx.x;
    const int t = threadIdx.x;
    float c = counts[g];
    if (c < 1.0f) c = 1.0f;
    gv[t] = sums[(size_t)g * HID + t] / c;
    __syncthreads();
    float acc = rb1[t];
    for (int k4 = 0; k4 < 32; ++k4) {
        float4 mv = *(const float4*)&gv[k4 * 4];
        #pragma unroll
        for (int j = 0; j < 4; ++j)
            acc += ((const float*)&mv)[j] * rw1[(size_t)(k4 * 4 + j) * HID + t];
    }
    hv[t] = silu_f(acc) * rw2[t];
    __syncthreads();
    for (int s = HID / 2; s > 0; s >>= 1) {
        if (t < s) hv[t] += hv[t + s];
        __syncthreads();
    }
    if (t == 0) pred[g] = hv[0] + rb2[0];
}

extern "C" void kernel_launch(void* const* d_in, const int* in_sizes, int n_in,
                              void* d_out, int out_size, void* d_ws, size_t ws_size,
                              hipStream_t stream) {
    const int*   z          = (const int*)d_in[0];
    const int*   edge_index = (const int*)d_in[1];
    const float* edge_attr  = (const float*)d_in[2];
    const int*   batch      = (const int*)d_in[3];
    const float* emb        = (const float*)d_in[4];
    const float* ew1        = (const float*)d_in[5];
    const float* eb1        = (const float*)d_in[6];
    const float* ew2        = (const float*)d_in[7];
    const float* eb2        = (const float*)d_in[8];
    const float* nw         = (const float*)d_in[9];
    const float* nb         = (const float*)d_in[10];
    const float* rw1        = (const float*)d_in[11];
    const float* rb1        = (const float*)d_in[12];
    const float* rw2        = (const float*)d_in[13];
    const float* rb2        = (const float*)d_in[14];
    float* pred = (float*)d_out;

    const int N = in_sizes[0];
    const int E = in_sizes[1] / 2;
    const int G = out_size;
    const int* srcI = edge_index;
    const int* dstI = edge_index + E;

    char* base = (char*)d_ws;
    size_t off = 0;
    auto carve = [&](size_t bytes) -> char* {
        char* p = base + off;
        off = (off + bytes + 255) & ~(size_t)255;
        return p;
    };
    float* agg    = (float*)carve((size_t)N * HID * sizeof(float));
    float* sums   = (float*)carve((size_t)G * HID * sizeof(float));
    float* counts = (float*)carve((size_t)G * sizeof(float));
    u16*   xb     = (u16*)carve((size_t)N * HID * sizeof(u16));
    u16*   eab    = (u16*)carve((size_t)E * EDIM * sizeof(u16));
    u16*   w1f    = (u16*)carve((size_t)4 * 72 * 512 * sizeof(u16)); // KT=9
    u16*   w2f    = (u16*)carve((size_t)4 * 32 * 512 * sizeof(u16)); // KT=4
    u16*   nwf    = (u16*)carve((size_t)4 * 64 * 512 * sizeof(u16)); // KT=8

    {
        int tot1 = 4 * 9 * 8 * 64;
        prep_wfrag<<<(tot1 + 255) / 256, 256, 0, stream>>>(ew1, w1f, 9, 2 * HID + EDIM, tot1);
        int tot2 = 4 * 4 * 8 * 64;
        prep_wfrag<<<(tot2 + 255) / 256, 256, 0, stream>>>(ew2, w2f, 4, HID, tot2);
        int tot3 = 4 * 8 * 8 * 64;
        prep_wfrag<<<(tot3 + 255) / 256, 256, 0, stream>>>(nw, nwf, 8, 2 * HID, tot3);
        int tote = E * EDIM;
        prep_ea<<<(tote + 255) / 256, 256, 0, stream>>>(edge_attr, eab, tote);
    }

    embed_kernel<<<N, HID, 0, stream>>>(z, emb, xb, N);

    for (int l = 0; l < 4; ++l) {
        hipMemsetAsync(agg, 0, (size_t)N * HID * sizeof(float), stream);
        edge_mfma<<<(E + 63) / 64, 256, 0, stream>>>(
            xb, srcI, dstI, eab,
            w1f + (size_t)l * 72 * 512, eb1 + (size_t)l * HID,
            w2f + (size_t)l * 32 * 512, eb2 + (size_t)l * HID,
            agg, E);
        node_mfma<<<(N + 63) / 64, 256, 0, stream>>>(
            xb, agg, nwf + (size_t)l * 64 * 512, nb + (size_t)l * HID, N);
    }

    hipMemsetAsync(sums,   0, (size_t)G * HID * sizeof(float), stream);
    hipMemsetAsync(counts, 0, (size_t)G * sizeof(float), stream);
    segsum_kernel<<<N, HID, 0, stream>>>(xb, batch, sums, counts, N);
    readout_kernel<<<G, HID, 0, stream>>>(sums, counts, rw1, rb1, rw2, rb2, pred);
}